// Round 6
// baseline (220.631 us; speedup 1.0000x reference)
//
#include <hip/hip_runtime.h>

// GCN layer: out = A_norm @ (h @ W^T + b), A_norm = D^-1/2 (A + I) D^-1/2
// Inputs: h [N,128] f32, W [128,128] f32, b [128] f32, edges [2,E] int32
// Output: [N,128] f32
//
// R6: algebraic weight fold — hs[i] = (h@W^T+b)[i] * rsqrt(deg[i]),
//     out[d] = rsqrt(deg[d]) * (hs[d] + sum_{s->d} hs[s]).
//     -> k_fill stores only src (no degf gathers, 4B payload),
//        k_agg needs no per-edge weight. Pipeline: count/scan first,
//        then MFMA linear (row-scaled), fill, gather-reduce.

#define IN_DIM 128
#define OUT_DIM 128

typedef short bf16x8 __attribute__((ext_vector_type(8)));
typedef float f32x4 __attribute__((ext_vector_type(4)));

__device__ __forceinline__ unsigned short f2bf(float f) {
    unsigned u = __float_as_uint(f);
    u += 0x7fffu + ((u >> 16) & 1u);  // round-nearest-even
    return (unsigned short)(u >> 16);
}

__global__ __launch_bounds__(256) void k_count(const int* __restrict__ dst,
                                               int* __restrict__ cnt, int E) {
    int e = blockIdx.x * 256 + threadIdx.x;
    if (e < E) atomicAdd(&cnt[dst[e]], 1);
}

// Pass 1: per-block (1024) exclusive scan of cnt -> off (block-local), block sum -> bsum.
__global__ __launch_bounds__(1024) void k_scan1(const int* __restrict__ cnt,
                                                int* __restrict__ off,
                                                int* __restrict__ bsum, int n) {
    __shared__ int wsum[16];
    const int tid = threadIdx.x;
    const int lane = tid & 63;
    const int wv = tid >> 6;
    int i = blockIdx.x * 1024 + tid;
    int v = (i < n) ? cnt[i] : 0;
    int x = v;
#pragma unroll
    for (int d = 1; d < 64; d <<= 1) {
        int t = __shfl_up(x, d, 64);
        if (lane >= d) x += t;
    }
    if (lane == 63) wsum[wv] = x;
    __syncthreads();
    if (wv == 0) {
        int y = (lane < 16) ? wsum[lane] : 0;
#pragma unroll
        for (int d = 1; d < 16; d <<= 1) {
            int t = __shfl_up(y, d, 64);
            if (lane >= d) y += t;
        }
        if (lane < 16) wsum[lane] = y;
    }
    __syncthreads();
    int waveoff = (wv == 0) ? 0 : wsum[wv - 1];
    if (i < n) off[i] = waveoff + x - v;
    if (tid == 0) bsum[blockIdx.x] = wsum[15];
}

// Pass 2: one wave scans nb (<=64) block sums -> bbase (exclusive); off[n] = total.
__global__ __launch_bounds__(64) void k_scan2(const int* __restrict__ bsum,
                                              int* __restrict__ bbase,
                                              int* __restrict__ off, int nb, int n) {
    int lane = threadIdx.x;
    int v = (lane < nb) ? bsum[lane] : 0;
    int x = v;
#pragma unroll
    for (int d = 1; d < 64; d <<= 1) {
        int t = __shfl_up(x, d, 64);
        if (lane >= d) x += t;
    }
    if (lane < nb) bbase[lane] = x - v;
    if (lane == nb - 1) off[n] = x;
}

// Pass 3: add block base; emit cursor copy and rs = rsqrt(deg) (incl self loop).
__global__ __launch_bounds__(1024) void k_scan3(const int* __restrict__ cnt,
                                                const int* __restrict__ bbase,
                                                int* __restrict__ off,
                                                int* __restrict__ cursor,
                                                float* __restrict__ rs, int n) {
    int i = blockIdx.x * 1024 + threadIdx.x;
    if (i >= n) return;
    int o = off[i] + bbase[blockIdx.x];
    off[i] = o;
    cursor[i] = o;
    rs[i] = rsqrtf((float)(cnt[i] + 1));
}

// Scatter edges into CSR buckets: src index only (weights folded into hs).
__global__ __launch_bounds__(256) void k_fill(const int* __restrict__ ed,
                                              int* __restrict__ cursor,
                                              int* __restrict__ csr_src, int E) {
    int e = blockIdx.x * 256 + threadIdx.x;
    if (e >= E) return;
    int s = ed[e];
    int d = ed[E + e];
    int pos = atomicAdd(&cursor[d], 1);
    csr_src[pos] = s;
}

// hs(bf16) = (h @ W^T + b) * rs[row], via MFMA 16x16x32 bf16.
// Block: 128 rows x 128 cols x K=128, 256 thr (4 waves), wave = 32 rows.
// C/D mapping: col=lane&15, row=quad*4+reg (m89-verified).
// LDS rows padded to 136 bf16 (272B -> 16-row stride aliases 2-way = free).
__global__ __launch_bounds__(256) void k_linear(const float* __restrict__ h,
                                                const float* __restrict__ W,
                                                const float* __restrict__ b,
                                                const float* __restrict__ rs,
                                                unsigned short* __restrict__ hsb, int n) {
    __shared__ unsigned short sA[128 * 136];  // h tile bf16
    __shared__ unsigned short sB[128 * 136];  // W bf16 (full, [n][k])

    const int tid = threadIdx.x;
    const int lane = tid & 63;
    const int wv = tid >> 6;
    const int quad = lane >> 4;
    const int l16 = lane & 15;
    const int row0 = blockIdx.x * 128;

    {
        const float4* h4 = (const float4*)h;
        const float4* W4 = (const float4*)W;
        for (int t = tid; t < 128 * 32; t += 256) {
            int r = t >> 5, c4 = t & 31;
            int row = row0 + r;
            float4 v = make_float4(0.f, 0.f, 0.f, 0.f);
            if (row < n) v = h4[(size_t)row * 32 + c4];
            ushort4 p;
            p.x = f2bf(v.x); p.y = f2bf(v.y); p.z = f2bf(v.z); p.w = f2bf(v.w);
            ((ushort4*)sA)[r * 34 + c4] = p;  // 136/4 = 34
            float4 w = W4[t];
            ushort4 q;
            q.x = f2bf(w.x); q.y = f2bf(w.y); q.z = f2bf(w.z); q.w = f2bf(w.w);
            ((ushort4*)sB)[r * 34 + c4] = q;
        }
    }
    __syncthreads();

    f32x4 acc[2][8];
#pragma unroll
    for (int mt = 0; mt < 2; ++mt)
#pragma unroll
        for (int nt = 0; nt < 8; ++nt) acc[mt][nt] = (f32x4){0.f, 0.f, 0.f, 0.f};

    const int koff = quad * 8;
#pragma unroll
    for (int kc = 0; kc < 4; ++kc) {
        int kbase = kc * 32 + koff;
        bf16x8 a0 = *(const bf16x8*)(sA + (wv * 32 + 0 + l16) * 136 + kbase);
        bf16x8 a1 = *(const bf16x8*)(sA + (wv * 32 + 16 + l16) * 136 + kbase);
#pragma unroll
        for (int nt = 0; nt < 8; ++nt) {
            bf16x8 bb = *(const bf16x8*)(sB + (nt * 16 + l16) * 136 + kbase);
            acc[0][nt] = __builtin_amdgcn_mfma_f32_16x16x32_bf16(a0, bb, acc[0][nt], 0, 0, 0);
            acc[1][nt] = __builtin_amdgcn_mfma_f32_16x16x32_bf16(a1, bb, acc[1][nt], 0, 0, 0);
        }
    }

    // epilogue: bias, scale by rs[row], bf16 store
#pragma unroll
    for (int mt = 0; mt < 2; ++mt) {
#pragma unroll
        for (int r = 0; r < 4; ++r) {
            int row = row0 + wv * 32 + mt * 16 + quad * 4 + r;
            if (row >= n) continue;
            float rsw = rs[row];
#pragma unroll
            for (int nt = 0; nt < 8; ++nt) {
                int col = nt * 16 + l16;
                hsb[(size_t)row * 128 + col] = f2bf((acc[mt][nt][r] + b[col]) * rsw);
            }
        }
    }
}

// One wave per node; lane = 2 channels packed in one uint (2x bf16).
// out[node] = rs[node] * (hs[node] + sum over CSR of hs[src]).  No weights.
__global__ __launch_bounds__(256) void k_agg(const int* __restrict__ off,
                                             const int* __restrict__ csr_src,
                                             const float* __restrict__ rs,
                                             const unsigned* __restrict__ hlb,
                                             float* __restrict__ out, int n) {
    int node = blockIdx.x * 4 + (threadIdx.x >> 6);
    if (node >= n) return;
    int lane = threadIdx.x & 63;
    int beg = off[node], end = off[node + 1];
    float rsn = rs[node];

    unsigned u = hlb[(size_t)node * 64 + lane];
    float2 acc;
    acc.x = __uint_as_float(u << 16);
    acc.y = __uint_as_float(u & 0xffff0000u);

    int e = beg;
    while ((e & 3) && e < end) {  // align to int4 boundary
        unsigned v = hlb[(size_t)csr_src[e] * 64 + lane];
        acc.x += __uint_as_float(v << 16);
        acc.y += __uint_as_float(v & 0xffff0000u);
        ++e;
    }
    const int4* csr4 = (const int4*)csr_src;
    for (; e + 8 <= end; e += 8) {  // 2 int4 loads + 8 gathers in flight
        int4 p0 = csr4[(e >> 2) + 0];
        int4 p1 = csr4[(e >> 2) + 1];
        unsigned v0 = hlb[(size_t)p0.x * 64 + lane];
        unsigned v1 = hlb[(size_t)p0.y * 64 + lane];
        unsigned v2 = hlb[(size_t)p0.z * 64 + lane];
        unsigned v3 = hlb[(size_t)p0.w * 64 + lane];
        unsigned v4 = hlb[(size_t)p1.x * 64 + lane];
        unsigned v5 = hlb[(size_t)p1.y * 64 + lane];
        unsigned v6 = hlb[(size_t)p1.z * 64 + lane];
        unsigned v7 = hlb[(size_t)p1.w * 64 + lane];
        acc.x += __uint_as_float(v0 << 16);
        acc.y += __uint_as_float(v0 & 0xffff0000u);
        acc.x += __uint_as_float(v1 << 16);
        acc.y += __uint_as_float(v1 & 0xffff0000u);
        acc.x += __uint_as_float(v2 << 16);
        acc.y += __uint_as_float(v2 & 0xffff0000u);
        acc.x += __uint_as_float(v3 << 16);
        acc.y += __uint_as_float(v3 & 0xffff0000u);
        acc.x += __uint_as_float(v4 << 16);
        acc.y += __uint_as_float(v4 & 0xffff0000u);
        acc.x += __uint_as_float(v5 << 16);
        acc.y += __uint_as_float(v5 & 0xffff0000u);
        acc.x += __uint_as_float(v6 << 16);
        acc.y += __uint_as_float(v6 & 0xffff0000u);
        acc.x += __uint_as_float(v7 << 16);
        acc.y += __uint_as_float(v7 & 0xffff0000u);
    }
    if (e + 4 <= end) {  // 4-edge chunk
        int4 p0 = csr4[e >> 2];
        unsigned v0 = hlb[(size_t)p0.x * 64 + lane];
        unsigned v1 = hlb[(size_t)p0.y * 64 + lane];
        unsigned v2 = hlb[(size_t)p0.z * 64 + lane];
        unsigned v3 = hlb[(size_t)p0.w * 64 + lane];
        acc.x += __uint_as_float(v0 << 16);
        acc.y += __uint_as_float(v0 & 0xffff0000u);
        acc.x += __uint_as_float(v1 << 16);
        acc.y += __uint_as_float(v1 & 0xffff0000u);
        acc.x += __uint_as_float(v2 << 16);
        acc.y += __uint_as_float(v2 & 0xffff0000u);
        acc.x += __uint_as_float(v3 << 16);
        acc.y += __uint_as_float(v3 & 0xffff0000u);
        e += 4;
    }
    for (; e < end; ++e) {
        unsigned v = hlb[(size_t)csr_src[e] * 64 + lane];
        acc.x += __uint_as_float(v << 16);
        acc.y += __uint_as_float(v & 0xffff0000u);
    }
    acc.x *= rsn;
    acc.y *= rsn;
    ((float2*)out)[(size_t)node * 64 + lane] = acc;
}

extern "C" void kernel_launch(void* const* d_in, const int* in_sizes, int n_in,
                              void* d_out, int out_size, void* d_ws, size_t ws_size,
                              hipStream_t stream) {
    const float* h = (const float*)d_in[0];
    const float* W = (const float*)d_in[1];
    const float* b = (const float*)d_in[2];
    const int* edges = (const int*)d_in[3];

    const int n = in_sizes[0] / IN_DIM;   // 50000
    const int E = in_sizes[3] / 2;        // 800000
    const int nb = (n + 1023) / 1024;     // 49 scan blocks

    // workspace carve-up (float units, each region 2KB-aligned)
    size_t o = 0;
    auto carve = [&](size_t elems) {
        size_t cur = o;
        o += (elems + 511) & ~(size_t)511;
        return cur;
    };
    float* ws = (float*)d_ws;
    unsigned short* hsb = (unsigned short*)(ws + carve((size_t)n * 64));  // n*128 bf16
    int*   cnt     = (int*)(ws + carve(n));
    int*   off     = (int*)(ws + carve(n + 1));
    int*   cursor  = (int*)(ws + carve(n));
    float* rs      = ws + carve(n);
    int*   bsum    = (int*)(ws + carve(64));
    int*   bbase   = (int*)(ws + carve(64));
    int*   csr_src = (int*)(ws + carve(E));

    float* out = (float*)d_out;

    hipMemsetAsync(cnt, 0, (size_t)n * sizeof(int), stream);
    k_count<<<(E + 255) / 256, 256, 0, stream>>>(edges + E, cnt, E);
    k_scan1<<<nb, 1024, 0, stream>>>(cnt, off, bsum, n);
    k_scan2<<<1, 64, 0, stream>>>(bsum, bbase, off, nb, n);
    k_scan3<<<nb, 1024, 0, stream>>>(cnt, bbase, off, cursor, rs, n);
    k_linear<<<(n + 127) / 128, 256, 0, stream>>>(h, W, b, rs, hsb, n);
    k_fill<<<(E + 255) / 256, 256, 0, stream>>>(edges, cursor, csr_src, E);
    k_agg<<<(n + 3) / 4, 256, 0, stream>>>(off, csr_src, rs,
                                           (const unsigned*)hsb, out, n);
}

// Round 7
// 212.200 us; speedup vs baseline: 1.0397x; 1.0397x over previous
//
#include <hip/hip_runtime.h>

// GCN layer: out = A_norm @ (h @ W^T + b), A_norm = D^-1/2 (A + I) D^-1/2
// Inputs: h [N,128] f32, W [128,128] f32, b [128] f32, edges [2,E] int32
// Output: [N,128] f32
//
// R7: XCD-partitioned k_fill. R6 showed csr_src scattered 4B stores suffer
// 16x write amplification (WRITE_SIZE 53MB for a 3.2MB array): lines get
// partially dirtied in all 8 non-coherent per-XCD L2s. Partition dst into
// 8 ranges; blocks on XCD x (blockIdx&7 round-robin heuristic) handle only
// range x, so each csr/cursor line is dirtied by exactly one XCD.
// Correct regardless of the actual block->XCD mapping.

#define IN_DIM 128
#define OUT_DIM 128

typedef short bf16x8 __attribute__((ext_vector_type(8)));
typedef float f32x4 __attribute__((ext_vector_type(4)));

__device__ __forceinline__ unsigned short f2bf(float f) {
    unsigned u = __float_as_uint(f);
    u += 0x7fffu + ((u >> 16) & 1u);  // round-nearest-even
    return (unsigned short)(u >> 16);
}

__global__ __launch_bounds__(256) void k_count(const int* __restrict__ dst,
                                               int* __restrict__ cnt, int E) {
    int e = blockIdx.x * 256 + threadIdx.x;
    if (e < E) atomicAdd(&cnt[dst[e]], 1);
}

// Pass 1: per-block (1024) exclusive scan of cnt -> off (block-local), block sum -> bsum.
__global__ __launch_bounds__(1024) void k_scan1(const int* __restrict__ cnt,
                                                int* __restrict__ off,
                                                int* __restrict__ bsum, int n) {
    __shared__ int wsum[16];
    const int tid = threadIdx.x;
    const int lane = tid & 63;
    const int wv = tid >> 6;
    int i = blockIdx.x * 1024 + tid;
    int v = (i < n) ? cnt[i] : 0;
    int x = v;
#pragma unroll
    for (int d = 1; d < 64; d <<= 1) {
        int t = __shfl_up(x, d, 64);
        if (lane >= d) x += t;
    }
    if (lane == 63) wsum[wv] = x;
    __syncthreads();
    if (wv == 0) {
        int y = (lane < 16) ? wsum[lane] : 0;
#pragma unroll
        for (int d = 1; d < 16; d <<= 1) {
            int t = __shfl_up(y, d, 64);
            if (lane >= d) y += t;
        }
        if (lane < 16) wsum[lane] = y;
    }
    __syncthreads();
    int waveoff = (wv == 0) ? 0 : wsum[wv - 1];
    if (i < n) off[i] = waveoff + x - v;
    if (tid == 0) bsum[blockIdx.x] = wsum[15];
}

// Pass 2: one wave scans nb (<=64) block sums -> bbase (exclusive); off[n] = total.
__global__ __launch_bounds__(64) void k_scan2(const int* __restrict__ bsum,
                                              int* __restrict__ bbase,
                                              int* __restrict__ off, int nb, int n) {
    int lane = threadIdx.x;
    int v = (lane < nb) ? bsum[lane] : 0;
    int x = v;
#pragma unroll
    for (int d = 1; d < 64; d <<= 1) {
        int t = __shfl_up(x, d, 64);
        if (lane >= d) x += t;
    }
    if (lane < nb) bbase[lane] = x - v;
    if (lane == nb - 1) off[n] = x;
}

// Pass 3: add block base; emit cursor copy and rs = rsqrt(deg) (incl self loop).
__global__ __launch_bounds__(1024) void k_scan3(const int* __restrict__ cnt,
                                                const int* __restrict__ bbase,
                                                int* __restrict__ off,
                                                int* __restrict__ cursor,
                                                float* __restrict__ rs, int n) {
    int i = blockIdx.x * 1024 + threadIdx.x;
    if (i >= n) return;
    int o = off[i] + bbase[blockIdx.x];
    off[i] = o;
    cursor[i] = o;
    rs[i] = rsqrtf((float)(cnt[i] + 1));
}

// XCD-partitioned CSR fill. Grid = 512 blocks = 64 edge-slices x 8 XCD lanes.
// Block (slice, xcd=blockIdx&7) scans its contiguous edge chunk and keeps
// edges with dst in [xcd*npx, (xcd+1)*npx).
__global__ __launch_bounds__(256) void k_fill(const int* __restrict__ ed,
                                              int* __restrict__ cursor,
                                              int* __restrict__ csr_src,
                                              int E, int npx) {
    const int xcd = blockIdx.x & 7;
    const int slice = blockIdx.x >> 3;
    const int nslices = gridDim.x >> 3;
    const int chunk = (E + nslices - 1) / nslices;
    const int e0 = slice * chunk;
    const int e1 = min(E, e0 + chunk);
    const int lo = xcd * npx;
    const int hi = lo + npx;
    const int* __restrict__ dstp = ed + E;
    for (int e = e0 + threadIdx.x; e < e1; e += 256) {
        int d = dstp[e];
        if (d >= lo && d < hi) {
            int s = ed[e];
            int pos = atomicAdd(&cursor[d], 1);
            csr_src[pos] = s;
        }
    }
}

// hs(bf16) = (h @ W^T + b) * rs[row], via MFMA 16x16x32 bf16.
// Block: 128 rows x 128 cols x K=128, 256 thr (4 waves), wave = 32 rows.
// C/D mapping: col=lane&15, row=quad*4+reg (m89-verified).
__global__ __launch_bounds__(256) void k_linear(const float* __restrict__ h,
                                                const float* __restrict__ W,
                                                const float* __restrict__ b,
                                                const float* __restrict__ rs,
                                                unsigned short* __restrict__ hsb, int n) {
    __shared__ unsigned short sA[128 * 136];  // h tile bf16
    __shared__ unsigned short sB[128 * 136];  // W bf16 (full, [n][k])

    const int tid = threadIdx.x;
    const int lane = tid & 63;
    const int wv = tid >> 6;
    const int quad = lane >> 4;
    const int l16 = lane & 15;
    const int row0 = blockIdx.x * 128;

    {
        const float4* h4 = (const float4*)h;
        const float4* W4 = (const float4*)W;
        for (int t = tid; t < 128 * 32; t += 256) {
            int r = t >> 5, c4 = t & 31;
            int row = row0 + r;
            float4 v = make_float4(0.f, 0.f, 0.f, 0.f);
            if (row < n) v = h4[(size_t)row * 32 + c4];
            ushort4 p;
            p.x = f2bf(v.x); p.y = f2bf(v.y); p.z = f2bf(v.z); p.w = f2bf(v.w);
            ((ushort4*)sA)[r * 34 + c4] = p;  // 136/4 = 34
            float4 w = W4[t];
            ushort4 q;
            q.x = f2bf(w.x); q.y = f2bf(w.y); q.z = f2bf(w.z); q.w = f2bf(w.w);
            ((ushort4*)sB)[r * 34 + c4] = q;
        }
    }
    __syncthreads();

    f32x4 acc[2][8];
#pragma unroll
    for (int mt = 0; mt < 2; ++mt)
#pragma unroll
        for (int nt = 0; nt < 8; ++nt) acc[mt][nt] = (f32x4){0.f, 0.f, 0.f, 0.f};

    const int koff = quad * 8;
#pragma unroll
    for (int kc = 0; kc < 4; ++kc) {
        int kbase = kc * 32 + koff;
        bf16x8 a0 = *(const bf16x8*)(sA + (wv * 32 + 0 + l16) * 136 + kbase);
        bf16x8 a1 = *(const bf16x8*)(sA + (wv * 32 + 16 + l16) * 136 + kbase);
#pragma unroll
        for (int nt = 0; nt < 8; ++nt) {
            bf16x8 bb = *(const bf16x8*)(sB + (nt * 16 + l16) * 136 + kbase);
            acc[0][nt] = __builtin_amdgcn_mfma_f32_16x16x32_bf16(a0, bb, acc[0][nt], 0, 0, 0);
            acc[1][nt] = __builtin_amdgcn_mfma_f32_16x16x32_bf16(a1, bb, acc[1][nt], 0, 0, 0);
        }
    }

    // epilogue: bias, scale by rs[row], bf16 store
#pragma unroll
    for (int mt = 0; mt < 2; ++mt) {
#pragma unroll
        for (int r = 0; r < 4; ++r) {
            int row = row0 + wv * 32 + mt * 16 + quad * 4 + r;
            if (row >= n) continue;
            float rsw = rs[row];
#pragma unroll
            for (int nt = 0; nt < 8; ++nt) {
                int col = nt * 16 + l16;
                hsb[(size_t)row * 128 + col] = f2bf((acc[mt][nt][r] + b[col]) * rsw);
            }
        }
    }
}

// One wave per node; lane = 2 channels packed in one uint (2x bf16).
// out[node] = rs[node] * (hs[node] + sum over CSR of hs[src]).
__global__ __launch_bounds__(256) void k_agg(const int* __restrict__ off,
                                             const int* __restrict__ csr_src,
                                             const float* __restrict__ rs,
                                             const unsigned* __restrict__ hlb,
                                             float* __restrict__ out, int n) {
    int node = blockIdx.x * 4 + (threadIdx.x >> 6);
    if (node >= n) return;
    int lane = threadIdx.x & 63;
    int beg = off[node], end = off[node + 1];
    float rsn = rs[node];

    unsigned u = hlb[(size_t)node * 64 + lane];
    float2 acc;
    acc.x = __uint_as_float(u << 16);
    acc.y = __uint_as_float(u & 0xffff0000u);

    int e = beg;
    while ((e & 3) && e < end) {  // align to int4 boundary
        unsigned v = hlb[(size_t)csr_src[e] * 64 + lane];
        acc.x += __uint_as_float(v << 16);
        acc.y += __uint_as_float(v & 0xffff0000u);
        ++e;
    }
    const int4* csr4 = (const int4*)csr_src;
    for (; e + 8 <= end; e += 8) {  // 2 int4 loads + 8 gathers in flight
        int4 p0 = csr4[(e >> 2) + 0];
        int4 p1 = csr4[(e >> 2) + 1];
        unsigned v0 = hlb[(size_t)p0.x * 64 + lane];
        unsigned v1 = hlb[(size_t)p0.y * 64 + lane];
        unsigned v2 = hlb[(size_t)p0.z * 64 + lane];
        unsigned v3 = hlb[(size_t)p0.w * 64 + lane];
        unsigned v4 = hlb[(size_t)p1.x * 64 + lane];
        unsigned v5 = hlb[(size_t)p1.y * 64 + lane];
        unsigned v6 = hlb[(size_t)p1.z * 64 + lane];
        unsigned v7 = hlb[(size_t)p1.w * 64 + lane];
        acc.x += __uint_as_float(v0 << 16);
        acc.y += __uint_as_float(v0 & 0xffff0000u);
        acc.x += __uint_as_float(v1 << 16);
        acc.y += __uint_as_float(v1 & 0xffff0000u);
        acc.x += __uint_as_float(v2 << 16);
        acc.y += __uint_as_float(v2 & 0xffff0000u);
        acc.x += __uint_as_float(v3 << 16);
        acc.y += __uint_as_float(v3 & 0xffff0000u);
        acc.x += __uint_as_float(v4 << 16);
        acc.y += __uint_as_float(v4 & 0xffff0000u);
        acc.x += __uint_as_float(v5 << 16);
        acc.y += __uint_as_float(v5 & 0xffff0000u);
        acc.x += __uint_as_float(v6 << 16);
        acc.y += __uint_as_float(v6 & 0xffff0000u);
        acc.x += __uint_as_float(v7 << 16);
        acc.y += __uint_as_float(v7 & 0xffff0000u);
    }
    if (e + 4 <= end) {
        int4 p0 = csr4[e >> 2];
        unsigned v0 = hlb[(size_t)p0.x * 64 + lane];
        unsigned v1 = hlb[(size_t)p0.y * 64 + lane];
        unsigned v2 = hlb[(size_t)p0.z * 64 + lane];
        unsigned v3 = hlb[(size_t)p0.w * 64 + lane];
        acc.x += __uint_as_float(v0 << 16);
        acc.y += __uint_as_float(v0 & 0xffff0000u);
        acc.x += __uint_as_float(v1 << 16);
        acc.y += __uint_as_float(v1 & 0xffff0000u);
        acc.x += __uint_as_float(v2 << 16);
        acc.y += __uint_as_float(v2 & 0xffff0000u);
        acc.x += __uint_as_float(v3 << 16);
        acc.y += __uint_as_float(v3 & 0xffff0000u);
        e += 4;
    }
    for (; e < end; ++e) {
        unsigned v = hlb[(size_t)csr_src[e] * 64 + lane];
        acc.x += __uint_as_float(v << 16);
        acc.y += __uint_as_float(v & 0xffff0000u);
    }
    acc.x *= rsn;
    acc.y *= rsn;
    ((float2*)out)[(size_t)node * 64 + lane] = acc;
}

extern "C" void kernel_launch(void* const* d_in, const int* in_sizes, int n_in,
                              void* d_out, int out_size, void* d_ws, size_t ws_size,
                              hipStream_t stream) {
    const float* h = (const float*)d_in[0];
    const float* W = (const float*)d_in[1];
    const float* b = (const float*)d_in[2];
    const int* edges = (const int*)d_in[3];

    const int n = in_sizes[0] / IN_DIM;   // 50000
    const int E = in_sizes[3] / 2;        // 800000
    const int nb = (n + 1023) / 1024;     // 49 scan blocks
    const int npx = (n + 7) / 8;          // nodes per XCD range (6250)

    // workspace carve-up (float units, each region 2KB-aligned)
    size_t o = 0;
    auto carve = [&](size_t elems) {
        size_t cur = o;
        o += (elems + 511) & ~(size_t)511;
        return cur;
    };
    float* ws = (float*)d_ws;
    unsigned short* hsb = (unsigned short*)(ws + carve((size_t)n * 64));  // n*128 bf16
    int*   cnt     = (int*)(ws + carve(n));
    int*   off     = (int*)(ws + carve(n + 1));
    int*   cursor  = (int*)(ws + carve(n));
    float* rs      = ws + carve(n);
    int*   bsum    = (int*)(ws + carve(64));
    int*   bbase   = (int*)(ws + carve(64));
    int*   csr_src = (int*)(ws + carve(E));

    float* out = (float*)d_out;

    hipMemsetAsync(cnt, 0, (size_t)n * sizeof(int), stream);
    k_count<<<(E + 255) / 256, 256, 0, stream>>>(edges + E, cnt, E);
    k_scan1<<<nb, 1024, 0, stream>>>(cnt, off, bsum, n);
    k_scan2<<<1, 64, 0, stream>>>(bsum, bbase, off, nb, n);
    k_scan3<<<nb, 1024, 0, stream>>>(cnt, bbase, off, cursor, rs, n);
    k_fill<<<512, 256, 0, stream>>>(edges, cursor, csr_src, E, npx);
    k_linear<<<(n + 127) / 128, 256, 0, stream>>>(h, W, b, rs, hsb, n);
    k_agg<<<(n + 3) / 4, 256, 0, stream>>>(off, csr_src, rs,
                                           (const unsigned*)hsb, out, n);
}

// Round 8
// 193.862 us; speedup vs baseline: 1.1381x; 1.0946x over previous
//
#include <hip/hip_runtime.h>

// GCN layer: out = A_norm @ (h @ W^T + b), A_norm = D^-1/2 (A + I) D^-1/2
// Inputs: h [N,128] f32, W [128,128] f32, b [128] f32, edges [2,E] int32
// Output: [N,128] f32
//
// R8: atomic-free k_fill. R7 showed fill is bound by the per-edge
// atomicAdd(cursor)->dependent-store chain (fabric round-trip each), not
// write traffic. Fix: k_count records rank[e] = atomicAdd(cnt[dst],1)
// (coalesced store); fill computes pos = off[dst] + rank[e] directly.
// XCD dst-partition kept for write locality (heuristic blockIdx&7).

#define IN_DIM 128
#define OUT_DIM 128

typedef short bf16x8 __attribute__((ext_vector_type(8)));
typedef float f32x4 __attribute__((ext_vector_type(4)));

__device__ __forceinline__ unsigned short f2bf(float f) {
    unsigned u = __float_as_uint(f);
    u += 0x7fffu + ((u >> 16) & 1u);  // round-nearest-even
    return (unsigned short)(u >> 16);
}

// Count degrees AND record each edge's arrival rank within its dst bucket.
__global__ __launch_bounds__(256) void k_count(const int* __restrict__ dst,
                                               int* __restrict__ cnt,
                                               int* __restrict__ rank, int E) {
    int e = blockIdx.x * 256 + threadIdx.x;
    if (e < E) rank[e] = atomicAdd(&cnt[dst[e]], 1);
}

// Pass 1: per-block (1024) exclusive scan of cnt -> off (block-local), block sum -> bsum.
__global__ __launch_bounds__(1024) void k_scan1(const int* __restrict__ cnt,
                                                int* __restrict__ off,
                                                int* __restrict__ bsum, int n) {
    __shared__ int wsum[16];
    const int tid = threadIdx.x;
    const int lane = tid & 63;
    const int wv = tid >> 6;
    int i = blockIdx.x * 1024 + tid;
    int v = (i < n) ? cnt[i] : 0;
    int x = v;
#pragma unroll
    for (int d = 1; d < 64; d <<= 1) {
        int t = __shfl_up(x, d, 64);
        if (lane >= d) x += t;
    }
    if (lane == 63) wsum[wv] = x;
    __syncthreads();
    if (wv == 0) {
        int y = (lane < 16) ? wsum[lane] : 0;
#pragma unroll
        for (int d = 1; d < 16; d <<= 1) {
            int t = __shfl_up(y, d, 64);
            if (lane >= d) y += t;
        }
        if (lane < 16) wsum[lane] = y;
    }
    __syncthreads();
    int waveoff = (wv == 0) ? 0 : wsum[wv - 1];
    if (i < n) off[i] = waveoff + x - v;
    if (tid == 0) bsum[blockIdx.x] = wsum[15];
}

// Pass 2: one wave scans nb (<=64) block sums -> bbase (exclusive); off[n] = total.
__global__ __launch_bounds__(64) void k_scan2(const int* __restrict__ bsum,
                                              int* __restrict__ bbase,
                                              int* __restrict__ off, int nb, int n) {
    int lane = threadIdx.x;
    int v = (lane < nb) ? bsum[lane] : 0;
    int x = v;
#pragma unroll
    for (int d = 1; d < 64; d <<= 1) {
        int t = __shfl_up(x, d, 64);
        if (lane >= d) x += t;
    }
    if (lane < nb) bbase[lane] = x - v;
    if (lane == nb - 1) off[n] = x;
}

// Pass 3: add block base; emit rs = rsqrt(deg) (incl self loop).
__global__ __launch_bounds__(1024) void k_scan3(const int* __restrict__ cnt,
                                                const int* __restrict__ bbase,
                                                int* __restrict__ off,
                                                float* __restrict__ rs, int n) {
    int i = blockIdx.x * 1024 + threadIdx.x;
    if (i >= n) return;
    off[i] = off[i] + bbase[blockIdx.x];
    rs[i] = rsqrtf((float)(cnt[i] + 1));
}

// Atomic-free CSR fill: pos = off[dst] + rank[e]. XCD-partitioned by dst
// range (blocks with blockIdx&7==x handle dst in [x*npx,(x+1)*npx)).
__global__ __launch_bounds__(256) void k_fill(const int* __restrict__ ed,
                                              const int* __restrict__ rank,
                                              const int* __restrict__ off,
                                              int* __restrict__ csr_src,
                                              int E, int npx) {
    const int xcd = blockIdx.x & 7;
    const int slice = blockIdx.x >> 3;
    const int nslices = gridDim.x >> 3;
    const int chunk = (E + nslices - 1) / nslices;
    const int e0 = slice * chunk;
    const int e1 = min(E, e0 + chunk);
    const int lo = xcd * npx;
    const int hi = lo + npx;
    const int* __restrict__ dstp = ed + E;
    for (int e = e0 + threadIdx.x; e < e1; e += 256) {
        int d = dstp[e];
        if (d >= lo && d < hi) {
            csr_src[off[d] + rank[e]] = ed[e];
        }
    }
}

// hs(bf16) = (h @ W^T + b) * rs[row], via MFMA 16x16x32 bf16.
// Block: 128 rows x 128 cols x K=128, 256 thr (4 waves), wave = 32 rows.
// C/D mapping: col=lane&15, row=quad*4+reg (m89-verified).
__global__ __launch_bounds__(256) void k_linear(const float* __restrict__ h,
                                                const float* __restrict__ W,
                                                const float* __restrict__ b,
                                                const float* __restrict__ rs,
                                                unsigned short* __restrict__ hsb, int n) {
    __shared__ unsigned short sA[128 * 136];  // h tile bf16
    __shared__ unsigned short sB[128 * 136];  // W bf16 (full, [n][k])

    const int tid = threadIdx.x;
    const int lane = tid & 63;
    const int wv = tid >> 6;
    const int quad = lane >> 4;
    const int l16 = lane & 15;
    const int row0 = blockIdx.x * 128;

    {
        const float4* h4 = (const float4*)h;
        const float4* W4 = (const float4*)W;
        for (int t = tid; t < 128 * 32; t += 256) {
            int r = t >> 5, c4 = t & 31;
            int row = row0 + r;
            float4 v = make_float4(0.f, 0.f, 0.f, 0.f);
            if (row < n) v = h4[(size_t)row * 32 + c4];
            ushort4 p;
            p.x = f2bf(v.x); p.y = f2bf(v.y); p.z = f2bf(v.z); p.w = f2bf(v.w);
            ((ushort4*)sA)[r * 34 + c4] = p;  // 136/4 = 34
            float4 w = W4[t];
            ushort4 q;
            q.x = f2bf(w.x); q.y = f2bf(w.y); q.z = f2bf(w.z); q.w = f2bf(w.w);
            ((ushort4*)sB)[r * 34 + c4] = q;
        }
    }
    __syncthreads();

    f32x4 acc[2][8];
#pragma unroll
    for (int mt = 0; mt < 2; ++mt)
#pragma unroll
        for (int nt = 0; nt < 8; ++nt) acc[mt][nt] = (f32x4){0.f, 0.f, 0.f, 0.f};

    const int koff = quad * 8;
#pragma unroll
    for (int kc = 0; kc < 4; ++kc) {
        int kbase = kc * 32 + koff;
        bf16x8 a0 = *(const bf16x8*)(sA + (wv * 32 + 0 + l16) * 136 + kbase);
        bf16x8 a1 = *(const bf16x8*)(sA + (wv * 32 + 16 + l16) * 136 + kbase);
#pragma unroll
        for (int nt = 0; nt < 8; ++nt) {
            bf16x8 bb = *(const bf16x8*)(sB + (nt * 16 + l16) * 136 + kbase);
            acc[0][nt] = __builtin_amdgcn_mfma_f32_16x16x32_bf16(a0, bb, acc[0][nt], 0, 0, 0);
            acc[1][nt] = __builtin_amdgcn_mfma_f32_16x16x32_bf16(a1, bb, acc[1][nt], 0, 0, 0);
        }
    }

    // epilogue: bias, scale by rs[row], bf16 store
#pragma unroll
    for (int mt = 0; mt < 2; ++mt) {
#pragma unroll
        for (int r = 0; r < 4; ++r) {
            int row = row0 + wv * 32 + mt * 16 + quad * 4 + r;
            if (row >= n) continue;
            float rsw = rs[row];
#pragma unroll
            for (int nt = 0; nt < 8; ++nt) {
                int col = nt * 16 + l16;
                hsb[(size_t)row * 128 + col] = f2bf((acc[mt][nt][r] + b[col]) * rsw);
            }
        }
    }
}

// One wave per node; lane = 2 channels packed in one uint (2x bf16).
// out[node] = rs[node] * (hs[node] + sum over CSR of hs[src]).
__global__ __launch_bounds__(256) void k_agg(const int* __restrict__ off,
                                             const int* __restrict__ csr_src,
                                             const float* __restrict__ rs,
                                             const unsigned* __restrict__ hlb,
                                             float* __restrict__ out, int n) {
    int node = blockIdx.x * 4 + (threadIdx.x >> 6);
    if (node >= n) return;
    int lane = threadIdx.x & 63;
    int beg = off[node], end = off[node + 1];
    float rsn = rs[node];

    unsigned u = hlb[(size_t)node * 64 + lane];
    float2 acc;
    acc.x = __uint_as_float(u << 16);
    acc.y = __uint_as_float(u & 0xffff0000u);

    int e = beg;
    while ((e & 3) && e < end) {  // align to int4 boundary
        unsigned v = hlb[(size_t)csr_src[e] * 64 + lane];
        acc.x += __uint_as_float(v << 16);
        acc.y += __uint_as_float(v & 0xffff0000u);
        ++e;
    }
    const int4* csr4 = (const int4*)csr_src;
    for (; e + 8 <= end; e += 8) {  // 2 int4 loads + 8 gathers in flight
        int4 p0 = csr4[(e >> 2) + 0];
        int4 p1 = csr4[(e >> 2) + 1];
        unsigned v0 = hlb[(size_t)p0.x * 64 + lane];
        unsigned v1 = hlb[(size_t)p0.y * 64 + lane];
        unsigned v2 = hlb[(size_t)p0.z * 64 + lane];
        unsigned v3 = hlb[(size_t)p0.w * 64 + lane];
        unsigned v4 = hlb[(size_t)p1.x * 64 + lane];
        unsigned v5 = hlb[(size_t)p1.y * 64 + lane];
        unsigned v6 = hlb[(size_t)p1.z * 64 + lane];
        unsigned v7 = hlb[(size_t)p1.w * 64 + lane];
        acc.x += __uint_as_float(v0 << 16);
        acc.y += __uint_as_float(v0 & 0xffff0000u);
        acc.x += __uint_as_float(v1 << 16);
        acc.y += __uint_as_float(v1 & 0xffff0000u);
        acc.x += __uint_as_float(v2 << 16);
        acc.y += __uint_as_float(v2 & 0xffff0000u);
        acc.x += __uint_as_float(v3 << 16);
        acc.y += __uint_as_float(v3 & 0xffff0000u);
        acc.x += __uint_as_float(v4 << 16);
        acc.y += __uint_as_float(v4 & 0xffff0000u);
        acc.x += __uint_as_float(v5 << 16);
        acc.y += __uint_as_float(v5 & 0xffff0000u);
        acc.x += __uint_as_float(v6 << 16);
        acc.y += __uint_as_float(v6 & 0xffff0000u);
        acc.x += __uint_as_float(v7 << 16);
        acc.y += __uint_as_float(v7 & 0xffff0000u);
    }
    if (e + 4 <= end) {
        int4 p0 = csr4[e >> 2];
        unsigned v0 = hlb[(size_t)p0.x * 64 + lane];
        unsigned v1 = hlb[(size_t)p0.y * 64 + lane];
        unsigned v2 = hlb[(size_t)p0.z * 64 + lane];
        unsigned v3 = hlb[(size_t)p0.w * 64 + lane];
        acc.x += __uint_as_float(v0 << 16);
        acc.y += __uint_as_float(v0 & 0xffff0000u);
        acc.x += __uint_as_float(v1 << 16);
        acc.y += __uint_as_float(v1 & 0xffff0000u);
        acc.x += __uint_as_float(v2 << 16);
        acc.y += __uint_as_float(v2 & 0xffff0000u);
        acc.x += __uint_as_float(v3 << 16);
        acc.y += __uint_as_float(v3 & 0xffff0000u);
        e += 4;
    }
    for (; e < end; ++e) {
        unsigned v = hlb[(size_t)csr_src[e] * 64 + lane];
        acc.x += __uint_as_float(v << 16);
        acc.y += __uint_as_float(v & 0xffff0000u);
    }
    acc.x *= rsn;
    acc.y *= rsn;
    ((float2*)out)[(size_t)node * 64 + lane] = acc;
}

extern "C" void kernel_launch(void* const* d_in, const int* in_sizes, int n_in,
                              void* d_out, int out_size, void* d_ws, size_t ws_size,
                              hipStream_t stream) {
    const float* h = (const float*)d_in[0];
    const float* W = (const float*)d_in[1];
    const float* b = (const float*)d_in[2];
    const int* edges = (const int*)d_in[3];

    const int n = in_sizes[0] / IN_DIM;   // 50000
    const int E = in_sizes[3] / 2;        // 800000
    const int nb = (n + 1023) / 1024;     // 49 scan blocks
    const int npx = (n + 7) / 8;          // nodes per XCD range (6250)

    // workspace carve-up (float units, each region 2KB-aligned)
    size_t o = 0;
    auto carve = [&](size_t elems) {
        size_t cur = o;
        o += (elems + 511) & ~(size_t)511;
        return cur;
    };
    float* ws = (float*)d_ws;
    unsigned short* hsb = (unsigned short*)(ws + carve((size_t)n * 64));  // n*128 bf16
    int*   cnt     = (int*)(ws + carve(n));
    int*   off     = (int*)(ws + carve(n + 1));
    int*   rank    = (int*)(ws + carve(E));
    float* rs      = ws + carve(n);
    int*   bsum    = (int*)(ws + carve(64));
    int*   bbase   = (int*)(ws + carve(64));
    int*   csr_src = (int*)(ws + carve(E));

    float* out = (float*)d_out;

    hipMemsetAsync(cnt, 0, (size_t)n * sizeof(int), stream);
    k_count<<<(E + 255) / 256, 256, 0, stream>>>(edges + E, cnt, rank, E);
    k_scan1<<<nb, 1024, 0, stream>>>(cnt, off, bsum, n);
    k_scan2<<<1, 64, 0, stream>>>(bsum, bbase, off, nb, n);
    k_scan3<<<nb, 1024, 0, stream>>>(cnt, bbase, off, rs, n);
    k_fill<<<1024, 256, 0, stream>>>(edges, rank, off, csr_src, E, npx);
    k_linear<<<(n + 127) / 128, 256, 0, stream>>>(h, W, b, rs, hsb, n);
    k_agg<<<(n + 3) / 4, 256, 0, stream>>>(off, csr_src, rs,
                                           (const unsigned*)hsb, out, n);
}

// Round 9
// 184.048 us; speedup vs baseline: 1.1988x; 1.0533x over previous
//
#include <hip/hip_runtime.h>

// GCN layer: out = A_norm @ (h @ W^T + b), A_norm = D^-1/2 (A + I) D^-1/2
// Inputs: h [N,128] f32, W [128,128] f32, b [128] f32, edges [2,E] int32
// Output: [N,128] f32
//
// R9: (1) single-pass atomic-free k_fill (R8's XCD partition cost 8x dst
//         reads and is unneeded once stores are independent),
//     (2) scan2 folded into scan3 (each block scans <=64 bsums itself),
//     (3) k_agg unroll 16 for deeper MLP (avg degree = 16).

#define IN_DIM 128
#define OUT_DIM 128

typedef short bf16x8 __attribute__((ext_vector_type(8)));
typedef float f32x4 __attribute__((ext_vector_type(4)));

__device__ __forceinline__ unsigned short f2bf(float f) {
    unsigned u = __float_as_uint(f);
    u += 0x7fffu + ((u >> 16) & 1u);  // round-nearest-even
    return (unsigned short)(u >> 16);
}

// Count degrees AND record each edge's arrival rank within its dst bucket.
__global__ __launch_bounds__(256) void k_count(const int* __restrict__ dst,
                                               int* __restrict__ cnt,
                                               int* __restrict__ rank, int E) {
    int e = blockIdx.x * 256 + threadIdx.x;
    if (e < E) rank[e] = atomicAdd(&cnt[dst[e]], 1);
}

// Pass 1: per-block (1024) exclusive scan of cnt -> off (block-local), block sum -> bsum.
__global__ __launch_bounds__(1024) void k_scan1(const int* __restrict__ cnt,
                                                int* __restrict__ off,
                                                int* __restrict__ bsum, int n) {
    __shared__ int wsum[16];
    const int tid = threadIdx.x;
    const int lane = tid & 63;
    const int wv = tid >> 6;
    int i = blockIdx.x * 1024 + tid;
    int v = (i < n) ? cnt[i] : 0;
    int x = v;
#pragma unroll
    for (int d = 1; d < 64; d <<= 1) {
        int t = __shfl_up(x, d, 64);
        if (lane >= d) x += t;
    }
    if (lane == 63) wsum[wv] = x;
    __syncthreads();
    if (wv == 0) {
        int y = (lane < 16) ? wsum[lane] : 0;
#pragma unroll
        for (int d = 1; d < 16; d <<= 1) {
            int t = __shfl_up(y, d, 64);
            if (lane >= d) y += t;
        }
        if (lane < 16) wsum[lane] = y;
    }
    __syncthreads();
    int waveoff = (wv == 0) ? 0 : wsum[wv - 1];
    if (i < n) off[i] = waveoff + x - v;
    if (tid == 0) bsum[blockIdx.x] = wsum[15];
}

// Pass 2 (fused): each block's wave 0 scans the <=64 block sums to get its
// own base; then all threads add base and emit rs. Block 0 writes off[n].
__global__ __launch_bounds__(1024) void k_scan3(const int* __restrict__ cnt,
                                                const int* __restrict__ bsum,
                                                int* __restrict__ off,
                                                float* __restrict__ rs,
                                                int n, int nb) {
    __shared__ int sbase;
    const int tid = threadIdx.x;
    if (tid < 64) {
        int v = (tid < nb) ? bsum[tid] : 0;
        int x = v;
#pragma unroll
        for (int d = 1; d < 64; d <<= 1) {
            int t = __shfl_up(x, d, 64);
            if (tid >= d) x += t;
        }
        if (tid == (int)blockIdx.x) sbase = x - v;       // exclusive base
        if (blockIdx.x == 0 && tid == nb - 1) off[n] = x;  // grand total
    }
    __syncthreads();
    int i = blockIdx.x * 1024 + tid;
    if (i >= n) return;
    off[i] = off[i] + sbase;
    rs[i] = rsqrtf((float)(cnt[i] + 1));
}

// Single-pass atomic-free CSR fill: pos = off[dst] + rank[e].
// 3 coalesced loads + 1 L2 gather (off) + 1 independent scattered store.
__global__ __launch_bounds__(256) void k_fill(const int* __restrict__ ed,
                                              const int* __restrict__ rank,
                                              const int* __restrict__ off,
                                              int* __restrict__ csr_src, int E) {
    int e = blockIdx.x * 256 + threadIdx.x;
    if (e >= E) return;
    int d = ed[E + e];
    csr_src[off[d] + rank[e]] = ed[e];
}

// hs(bf16) = (h @ W^T + b) * rs[row], via MFMA 16x16x32 bf16.
// Block: 128 rows x 128 cols x K=128, 256 thr (4 waves), wave = 32 rows.
// C/D mapping: col=lane&15, row=quad*4+reg (m89-verified).
__global__ __launch_bounds__(256) void k_linear(const float* __restrict__ h,
                                                const float* __restrict__ W,
                                                const float* __restrict__ b,
                                                const float* __restrict__ rs,
                                                unsigned short* __restrict__ hsb, int n) {
    __shared__ unsigned short sA[128 * 136];  // h tile bf16
    __shared__ unsigned short sB[128 * 136];  // W bf16 (full, [n][k])

    const int tid = threadIdx.x;
    const int lane = tid & 63;
    const int wv = tid >> 6;
    const int quad = lane >> 4;
    const int l16 = lane & 15;
    const int row0 = blockIdx.x * 128;

    {
        const float4* h4 = (const float4*)h;
        const float4* W4 = (const float4*)W;
        for (int t = tid; t < 128 * 32; t += 256) {
            int r = t >> 5, c4 = t & 31;
            int row = row0 + r;
            float4 v = make_float4(0.f, 0.f, 0.f, 0.f);
            if (row < n) v = h4[(size_t)row * 32 + c4];
            ushort4 p;
            p.x = f2bf(v.x); p.y = f2bf(v.y); p.z = f2bf(v.z); p.w = f2bf(v.w);
            ((ushort4*)sA)[r * 34 + c4] = p;  // 136/4 = 34
            float4 w = W4[t];
            ushort4 q;
            q.x = f2bf(w.x); q.y = f2bf(w.y); q.z = f2bf(w.z); q.w = f2bf(w.w);
            ((ushort4*)sB)[r * 34 + c4] = q;
        }
    }
    __syncthreads();

    f32x4 acc[2][8];
#pragma unroll
    for (int mt = 0; mt < 2; ++mt)
#pragma unroll
        for (int nt = 0; nt < 8; ++nt) acc[mt][nt] = (f32x4){0.f, 0.f, 0.f, 0.f};

    const int koff = quad * 8;
#pragma unroll
    for (int kc = 0; kc < 4; ++kc) {
        int kbase = kc * 32 + koff;
        bf16x8 a0 = *(const bf16x8*)(sA + (wv * 32 + 0 + l16) * 136 + kbase);
        bf16x8 a1 = *(const bf16x8*)(sA + (wv * 32 + 16 + l16) * 136 + kbase);
#pragma unroll
        for (int nt = 0; nt < 8; ++nt) {
            bf16x8 bb = *(const bf16x8*)(sB + (nt * 16 + l16) * 136 + kbase);
            acc[0][nt] = __builtin_amdgcn_mfma_f32_16x16x32_bf16(a0, bb, acc[0][nt], 0, 0, 0);
            acc[1][nt] = __builtin_amdgcn_mfma_f32_16x16x32_bf16(a1, bb, acc[1][nt], 0, 0, 0);
        }
    }

    // epilogue: bias, scale by rs[row], bf16 store
#pragma unroll
    for (int mt = 0; mt < 2; ++mt) {
#pragma unroll
        for (int r = 0; r < 4; ++r) {
            int row = row0 + wv * 32 + mt * 16 + quad * 4 + r;
            if (row >= n) continue;
            float rsw = rs[row];
#pragma unroll
            for (int nt = 0; nt < 8; ++nt) {
                int col = nt * 16 + l16;
                hsb[(size_t)row * 128 + col] = f2bf((acc[mt][nt][r] + b[col]) * rsw);
            }
        }
    }
}

// One wave per node; lane = 2 channels packed in one uint (2x bf16).
// out[node] = rs[node] * (hs[node] + sum over CSR of hs[src]).
#define ACC2(v)                                \
    acc.x += __uint_as_float((v) << 16);       \
    acc.y += __uint_as_float((v) & 0xffff0000u)
__global__ __launch_bounds__(256) void k_agg(const int* __restrict__ off,
                                             const int* __restrict__ csr_src,
                                             const float* __restrict__ rs,
                                             const unsigned* __restrict__ hlb,
                                             float* __restrict__ out, int n) {
    int node = blockIdx.x * 4 + (threadIdx.x >> 6);
    if (node >= n) return;
    int lane = threadIdx.x & 63;
    int beg = off[node], end = off[node + 1];
    float rsn = rs[node];

    unsigned u = hlb[(size_t)node * 64 + lane];
    float2 acc;
    acc.x = __uint_as_float(u << 16);
    acc.y = __uint_as_float(u & 0xffff0000u);

    int e = beg;
    while ((e & 3) && e < end) {  // align to int4 boundary
        unsigned v = hlb[(size_t)csr_src[e] * 64 + lane];
        ACC2(v);
        ++e;
    }
    const int4* csr4 = (const int4*)csr_src;
    for (; e + 16 <= end; e += 16) {  // 4 int4 loads + 16 gathers in flight
        int4 p0 = csr4[(e >> 2) + 0];
        int4 p1 = csr4[(e >> 2) + 1];
        int4 p2 = csr4[(e >> 2) + 2];
        int4 p3 = csr4[(e >> 2) + 3];
        unsigned v0 = hlb[(size_t)p0.x * 64 + lane];
        unsigned v1 = hlb[(size_t)p0.y * 64 + lane];
        unsigned v2 = hlb[(size_t)p0.z * 64 + lane];
        unsigned v3 = hlb[(size_t)p0.w * 64 + lane];
        unsigned v4 = hlb[(size_t)p1.x * 64 + lane];
        unsigned v5 = hlb[(size_t)p1.y * 64 + lane];
        unsigned v6 = hlb[(size_t)p1.z * 64 + lane];
        unsigned v7 = hlb[(size_t)p1.w * 64 + lane];
        unsigned v8 = hlb[(size_t)p2.x * 64 + lane];
        unsigned v9 = hlb[(size_t)p2.y * 64 + lane];
        unsigned va = hlb[(size_t)p2.z * 64 + lane];
        unsigned vb = hlb[(size_t)p2.w * 64 + lane];
        unsigned vc = hlb[(size_t)p3.x * 64 + lane];
        unsigned vd = hlb[(size_t)p3.y * 64 + lane];
        unsigned ve = hlb[(size_t)p3.z * 64 + lane];
        unsigned vf = hlb[(size_t)p3.w * 64 + lane];
        ACC2(v0); ACC2(v1); ACC2(v2); ACC2(v3);
        ACC2(v4); ACC2(v5); ACC2(v6); ACC2(v7);
        ACC2(v8); ACC2(v9); ACC2(va); ACC2(vb);
        ACC2(vc); ACC2(vd); ACC2(ve); ACC2(vf);
    }
    if (e + 8 <= end) {
        int4 p0 = csr4[(e >> 2) + 0];
        int4 p1 = csr4[(e >> 2) + 1];
        unsigned v0 = hlb[(size_t)p0.x * 64 + lane];
        unsigned v1 = hlb[(size_t)p0.y * 64 + lane];
        unsigned v2 = hlb[(size_t)p0.z * 64 + lane];
        unsigned v3 = hlb[(size_t)p0.w * 64 + lane];
        unsigned v4 = hlb[(size_t)p1.x * 64 + lane];
        unsigned v5 = hlb[(size_t)p1.y * 64 + lane];
        unsigned v6 = hlb[(size_t)p1.z * 64 + lane];
        unsigned v7 = hlb[(size_t)p1.w * 64 + lane];
        ACC2(v0); ACC2(v1); ACC2(v2); ACC2(v3);
        ACC2(v4); ACC2(v5); ACC2(v6); ACC2(v7);
        e += 8;
    }
    if (e + 4 <= end) {
        int4 p0 = csr4[e >> 2];
        unsigned v0 = hlb[(size_t)p0.x * 64 + lane];
        unsigned v1 = hlb[(size_t)p0.y * 64 + lane];
        unsigned v2 = hlb[(size_t)p0.z * 64 + lane];
        unsigned v3 = hlb[(size_t)p0.w * 64 + lane];
        ACC2(v0); ACC2(v1); ACC2(v2); ACC2(v3);
        e += 4;
    }
    for (; e < end; ++e) {
        unsigned v = hlb[(size_t)csr_src[e] * 64 + lane];
        ACC2(v);
    }
    acc.x *= rsn;
    acc.y *= rsn;
    ((float2*)out)[(size_t)node * 64 + lane] = acc;
}

extern "C" void kernel_launch(void* const* d_in, const int* in_sizes, int n_in,
                              void* d_out, int out_size, void* d_ws, size_t ws_size,
                              hipStream_t stream) {
    const float* h = (const float*)d_in[0];
    const float* W = (const float*)d_in[1];
    const float* b = (const float*)d_in[2];
    const int* edges = (const int*)d_in[3];

    const int n = in_sizes[0] / IN_DIM;   // 50000
    const int E = in_sizes[3] / 2;        // 800000
    const int nb = (n + 1023) / 1024;     // 49 scan blocks (<=64 required)

    // workspace carve-up (float units, each region 2KB-aligned)
    size_t o = 0;
    auto carve = [&](size_t elems) {
        size_t cur = o;
        o += (elems + 511) & ~(size_t)511;
        return cur;
    };
    float* ws = (float*)d_ws;
    unsigned short* hsb = (unsigned short*)(ws + carve((size_t)n * 64));  // n*128 bf16
    int*   cnt     = (int*)(ws + carve(n));
    int*   off     = (int*)(ws + carve(n + 1));
    int*   rank    = (int*)(ws + carve(E));
    float* rs      = ws + carve(n);
    int*   bsum    = (int*)(ws + carve(64));
    int*   csr_src = (int*)(ws + carve(E));

    float* out = (float*)d_out;

    hipMemsetAsync(cnt, 0, (size_t)n * sizeof(int), stream);
    k_count<<<(E + 255) / 256, 256, 0, stream>>>(edges + E, cnt, rank, E);
    k_scan1<<<nb, 1024, 0, stream>>>(cnt, off, bsum, n);
    k_scan3<<<nb, 1024, 0, stream>>>(cnt, bsum, off, rs, n, nb);
    k_fill<<<(E + 255) / 256, 256, 0, stream>>>(edges, rank, off, csr_src, E);
    k_linear<<<(n + 127) / 128, 256, 0, stream>>>(h, W, b, rs, hsb, n);
    k_agg<<<(n + 3) / 4, 256, 0, stream>>>(off, csr_src, rs,
                                           (const unsigned*)hsb, out, n);
}

// Round 10
// 180.870 us; speedup vs baseline: 1.2198x; 1.0176x over previous
//
#include <hip/hip_runtime.h>

// GCN layer: out = A_norm @ (h @ W^T + b), A_norm = D^-1/2 (A + I) D^-1/2
// Inputs: h [N,128] f32, W [128,128] f32, b [128] f32, edges [2,E] int32
// Output: [N,128] f32
//
// R10: (1) k_agg half-wave-per-node with ushort4 gathers: one gather inst
//          serves 2 edges, one int4 index load serves 8 edges (same
//          per-channel accumulation order -> bitwise-identical output).
//      (2) k_fill fused into k_linear (block-split): scattered-store
//          latency hides under MFMA; one fewer launch.

#define IN_DIM 128
#define OUT_DIM 128

typedef short bf16x8 __attribute__((ext_vector_type(8)));
typedef float f32x4 __attribute__((ext_vector_type(4)));

__device__ __forceinline__ unsigned short f2bf(float f) {
    unsigned u = __float_as_uint(f);
    u += 0x7fffu + ((u >> 16) & 1u);  // round-nearest-even
    return (unsigned short)(u >> 16);
}
__device__ __forceinline__ float bf2f(unsigned short s) {
    return __uint_as_float(((unsigned)s) << 16);
}

// Count degrees AND record each edge's arrival rank within its dst bucket.
__global__ __launch_bounds__(256) void k_count(const int* __restrict__ dst,
                                               int* __restrict__ cnt,
                                               int* __restrict__ rank, int E) {
    int e = blockIdx.x * 256 + threadIdx.x;
    if (e < E) rank[e] = atomicAdd(&cnt[dst[e]], 1);
}

// Pass 1: per-block (1024) exclusive scan of cnt -> off (block-local), block sum -> bsum.
__global__ __launch_bounds__(1024) void k_scan1(const int* __restrict__ cnt,
                                                int* __restrict__ off,
                                                int* __restrict__ bsum, int n) {
    __shared__ int wsum[16];
    const int tid = threadIdx.x;
    const int lane = tid & 63;
    const int wv = tid >> 6;
    int i = blockIdx.x * 1024 + tid;
    int v = (i < n) ? cnt[i] : 0;
    int x = v;
#pragma unroll
    for (int d = 1; d < 64; d <<= 1) {
        int t = __shfl_up(x, d, 64);
        if (lane >= d) x += t;
    }
    if (lane == 63) wsum[wv] = x;
    __syncthreads();
    if (wv == 0) {
        int y = (lane < 16) ? wsum[lane] : 0;
#pragma unroll
        for (int d = 1; d < 16; d <<= 1) {
            int t = __shfl_up(y, d, 64);
            if (lane >= d) y += t;
        }
        if (lane < 16) wsum[lane] = y;
    }
    __syncthreads();
    int waveoff = (wv == 0) ? 0 : wsum[wv - 1];
    if (i < n) off[i] = waveoff + x - v;
    if (tid == 0) bsum[blockIdx.x] = wsum[15];
}

// Pass 2 (fused): each block's wave 0 scans the <=64 block sums to get its
// own base; then all threads add base and emit rs. Block 0 writes off[n].
__global__ __launch_bounds__(1024) void k_scan3(const int* __restrict__ cnt,
                                                const int* __restrict__ bsum,
                                                int* __restrict__ off,
                                                float* __restrict__ rs,
                                                int n, int nb) {
    __shared__ int sbase;
    const int tid = threadIdx.x;
    if (tid < 64) {
        int v = (tid < nb) ? bsum[tid] : 0;
        int x = v;
#pragma unroll
        for (int d = 1; d < 64; d <<= 1) {
            int t = __shfl_up(x, d, 64);
            if (tid >= d) x += t;
        }
        if (tid == (int)blockIdx.x) sbase = x - v;         // exclusive base
        if (blockIdx.x == 0 && tid == nb - 1) off[n] = x;  // grand total
    }
    __syncthreads();
    int i = blockIdx.x * 1024 + tid;
    if (i >= n) return;
    off[i] = off[i] + sbase;
    rs[i] = rsqrtf((float)(cnt[i] + 1));
}

// Fused: blocks [0,nlin) compute hs = (h@W^T+b)*rs via MFMA;
// blocks [nlin, nlin+NFB) do the atomic-free CSR fill (grid-stride chunks).
// Fill's scattered stores overlap the GEMM instead of serializing after it.
#define NFB 1024
__global__ __launch_bounds__(256) void k_fill_linear(
        const float* __restrict__ h, const float* __restrict__ W,
        const float* __restrict__ b, const float* __restrict__ rs,
        unsigned short* __restrict__ hsb, int n,
        const int* __restrict__ ed, const int* __restrict__ rank,
        const int* __restrict__ off, int* __restrict__ csr_src, int E,
        int nlin) {
    if ((int)blockIdx.x >= nlin) {
        // ---- CSR fill: pos = off[dst] + rank[e], independent stores ----
        int fb = blockIdx.x - nlin;
        int chunk = (E + NFB - 1) / NFB;
        int e1 = min(E, fb * chunk + chunk);
        for (int e = fb * chunk + threadIdx.x; e < e1; e += 256) {
            int d = ed[E + e];
            csr_src[off[d] + rank[e]] = ed[e];
        }
        return;
    }
    // ---- MFMA linear: 128x128 tile, K=128, 4 waves ----
    __shared__ unsigned short sA[128 * 136];  // h tile bf16 (+8 pad)
    __shared__ unsigned short sB[128 * 136];  // W bf16 [n][k]

    const int tid = threadIdx.x;
    const int lane = tid & 63;
    const int wv = tid >> 6;
    const int quad = lane >> 4;
    const int l16 = lane & 15;
    const int row0 = blockIdx.x * 128;

    {
        const float4* h4 = (const float4*)h;
        const float4* W4 = (const float4*)W;
        for (int t = tid; t < 128 * 32; t += 256) {
            int r = t >> 5, c4 = t & 31;
            int row = row0 + r;
            float4 v = make_float4(0.f, 0.f, 0.f, 0.f);
            if (row < n) v = h4[(size_t)row * 32 + c4];
            ushort4 p;
            p.x = f2bf(v.x); p.y = f2bf(v.y); p.z = f2bf(v.z); p.w = f2bf(v.w);
            ((ushort4*)sA)[r * 34 + c4] = p;  // 136/4 = 34
            float4 w = W4[t];
            ushort4 q;
            q.x = f2bf(w.x); q.y = f2bf(w.y); q.z = f2bf(w.z); q.w = f2bf(w.w);
            ((ushort4*)sB)[r * 34 + c4] = q;
        }
    }
    __syncthreads();

    f32x4 acc[2][8];
#pragma unroll
    for (int mt = 0; mt < 2; ++mt)
#pragma unroll
        for (int nt = 0; nt < 8; ++nt) acc[mt][nt] = (f32x4){0.f, 0.f, 0.f, 0.f};

    const int koff = quad * 8;
#pragma unroll
    for (int kc = 0; kc < 4; ++kc) {
        int kbase = kc * 32 + koff;
        bf16x8 a0 = *(const bf16x8*)(sA + (wv * 32 + 0 + l16) * 136 + kbase);
        bf16x8 a1 = *(const bf16x8*)(sA + (wv * 32 + 16 + l16) * 136 + kbase);
#pragma unroll
        for (int nt = 0; nt < 8; ++nt) {
            bf16x8 bb = *(const bf16x8*)(sB + (nt * 16 + l16) * 136 + kbase);
            acc[0][nt] = __builtin_amdgcn_mfma_f32_16x16x32_bf16(a0, bb, acc[0][nt], 0, 0, 0);
            acc[1][nt] = __builtin_amdgcn_mfma_f32_16x16x32_bf16(a1, bb, acc[1][nt], 0, 0, 0);
        }
    }

    // epilogue: bias, scale by rs[row], bf16 store
#pragma unroll
    for (int mt = 0; mt < 2; ++mt) {
#pragma unroll
        for (int r = 0; r < 4; ++r) {
            int row = row0 + wv * 32 + mt * 16 + quad * 4 + r;
            if (row >= n) continue;
            float rsw = rs[row];
#pragma unroll
            for (int nt = 0; nt < 8; ++nt) {
                int col = nt * 16 + l16;
                hsb[(size_t)row * 128 + col] = f2bf((acc[mt][nt][r] + b[col]) * rsw);
            }
        }
    }
}

// Half-wave (32 lanes) per node; lane = 4 channels (ushort4 = 8B).
// One gather instruction serves 2 edges (2 half-waves); int4 index load
// serves 8. out[node] = rs[node] * (hs[node] + sum hs[src]).
#define ACC4(v)               \
    acc.x += bf2f((v).x);     \
    acc.y += bf2f((v).y);     \
    acc.z += bf2f((v).z);     \
    acc.w += bf2f((v).w)
__global__ __launch_bounds__(256) void k_agg(const int* __restrict__ off,
                                             const int* __restrict__ csr_src,
                                             const float* __restrict__ rs,
                                             const unsigned short* __restrict__ hsb,
                                             float* __restrict__ out, int n) {
    int node = blockIdx.x * 8 + (threadIdx.x >> 5);
    if (node >= n) return;
    int lane = threadIdx.x & 31;
    int beg = off[node], end = off[node + 1];
    float rsn = rs[node];

    const ushort4* hp = (const ushort4*)hsb;  // row = 32 ushort4
    ushort4 sv = hp[(size_t)node * 32 + lane];
    float4 acc;
    acc.x = bf2f(sv.x); acc.y = bf2f(sv.y); acc.z = bf2f(sv.z); acc.w = bf2f(sv.w);

    int e = beg;
    while ((e & 3) && e < end) {  // align to int4 boundary
        ushort4 v = hp[(size_t)csr_src[e] * 32 + lane];
        ACC4(v);
        ++e;
    }
    const int4* csr4 = (const int4*)csr_src;
    for (; e + 8 <= end; e += 8) {  // 2 int4 loads + 8 row gathers in flight
        int4 p0 = csr4[(e >> 2) + 0];
        int4 p1 = csr4[(e >> 2) + 1];
        ushort4 v0 = hp[(size_t)p0.x * 32 + lane];
        ushort4 v1 = hp[(size_t)p0.y * 32 + lane];
        ushort4 v2 = hp[(size_t)p0.z * 32 + lane];
        ushort4 v3 = hp[(size_t)p0.w * 32 + lane];
        ushort4 v4 = hp[(size_t)p1.x * 32 + lane];
        ushort4 v5 = hp[(size_t)p1.y * 32 + lane];
        ushort4 v6 = hp[(size_t)p1.z * 32 + lane];
        ushort4 v7 = hp[(size_t)p1.w * 32 + lane];
        ACC4(v0); ACC4(v1); ACC4(v2); ACC4(v3);
        ACC4(v4); ACC4(v5); ACC4(v6); ACC4(v7);
    }
    if (e + 4 <= end) {
        int4 p0 = csr4[e >> 2];
        ushort4 v0 = hp[(size_t)p0.x * 32 + lane];
        ushort4 v1 = hp[(size_t)p0.y * 32 + lane];
        ushort4 v2 = hp[(size_t)p0.z * 32 + lane];
        ushort4 v3 = hp[(size_t)p0.w * 32 + lane];
        ACC4(v0); ACC4(v1); ACC4(v2); ACC4(v3);
        e += 4;
    }
    for (; e < end; ++e) {
        ushort4 v = hp[(size_t)csr_src[e] * 32 + lane];
        ACC4(v);
    }
    acc.x *= rsn; acc.y *= rsn; acc.z *= rsn; acc.w *= rsn;
    ((float4*)out)[(size_t)node * 32 + lane] = acc;
}

extern "C" void kernel_launch(void* const* d_in, const int* in_sizes, int n_in,
                              void* d_out, int out_size, void* d_ws, size_t ws_size,
                              hipStream_t stream) {
    const float* h = (const float*)d_in[0];
    const float* W = (const float*)d_in[1];
    const float* b = (const float*)d_in[2];
    const int* edges = (const int*)d_in[3];

    const int n = in_sizes[0] / IN_DIM;   // 50000
    const int E = in_sizes[3] / 2;        // 800000
    const int nb = (n + 1023) / 1024;     // 49 scan blocks (<=64 required)
    const int nlin = (n + 127) / 128;     // 391 GEMM tiles

    // workspace carve-up (float units, each region 2KB-aligned)
    size_t o = 0;
    auto carve = [&](size_t elems) {
        size_t cur = o;
        o += (elems + 511) & ~(size_t)511;
        return cur;
    };
    float* ws = (float*)d_ws;
    unsigned short* hsb = (unsigned short*)(ws + carve((size_t)n * 64));  // n*128 bf16
    int*   cnt     = (int*)(ws + carve(n));
    int*   off     = (int*)(ws + carve(n + 1));
    int*   rank    = (int*)(ws + carve(E));
    float* rs      = ws + carve(n);
    int*   bsum    = (int*)(ws + carve(64));
    int*   csr_src = (int*)(ws + carve(E));

    float* out = (float*)d_out;

    hipMemsetAsync(cnt, 0, (size_t)n * sizeof(int), stream);
    k_count<<<(E + 255) / 256, 256, 0, stream>>>(edges + E, cnt, rank, E);
    k_scan1<<<nb, 1024, 0, stream>>>(cnt, off, bsum, n);
    k_scan3<<<nb, 1024, 0, stream>>>(cnt, bsum, off, rs, n, nb);
    k_fill_linear<<<nlin + NFB, 256, 0, stream>>>(h, W, b, rs, hsb, n,
                                                  edges, rank, off, csr_src, E, nlin);
    k_agg<<<(n + 7) / 8, 256, 0, stream>>>(off, csr_src, rs, hsb, out, n);
}